// Round 1
// baseline (477.704 us; speedup 1.0000x reference)
//
#include <hip/hip_runtime.h>
#include <hip/hip_bf16.h>

// ---------------------------------------------------------------------------
// PolicyValueNet forward on MI355X.
// Workspace layout (floats):
//   xA      @ 0        : 25600   [400][64] fmap ping
//   xB      @ 25600    : 25600   [400][64] fmap pong
//   wT      @ 51200    : 294912  8 convs x [ic64][tap9][oc64]
//   vwT     @ 346112   : 2048    val 1x1 conv [ic64][oc32]
//   emb_h   @ 348160   : 2688    [21][128] piece_table@W1[64:80] + b1
//   pooled  @ 350848   : 32      value-head pooled sum (zeroed in prep)
//   fbf     @ 350880   : 13600 floats = 27200 bf16, fmap [400][68] (pitch-68)
// Total: 364480 floats = 1,457,920 bytes.
// ---------------------------------------------------------------------------

typedef unsigned short ushort_t;

// ---------------- prep (+ stem on blocks 0..99) ----------------
__global__ __launch_bounds__(256) void prep_stem_kernel(
    const float* __restrict__ board,
    const float* __restrict__ stem_w, const float* __restrict__ stem_b,
    const float* __restrict__ stem_s, const float* __restrict__ stem_o,
    float* __restrict__ xA,
    const float* __restrict__ blk_w1, const float* __restrict__ blk_w2,
    const float* __restrict__ val_conv_w, const float* __restrict__ piece_table,
    const float* __restrict__ mlp_w1, const float* __restrict__ mlp_b1,
    float* __restrict__ wT, float* __restrict__ vwT,
    float* __restrict__ emb_h, float* __restrict__ pooled)
{
    int g  = blockIdx.x * blockDim.x + threadIdx.x;
    int gs = gridDim.x * blockDim.x;

    // transpose residual conv weights: [l][oc][ic][9] -> [l][ic][tap][oc]
    for (int i = g; i < 294912; i += gs) {
        int oc  = i & 63;
        int tap = (i >> 6) % 9;
        int ic  = (i / 576) & 63;
        int l   = i / 36864;
        const float* src = (l & 1) ? blk_w2 : blk_w1;
        wT[i] = src[(l >> 1) * 36864 + oc * 576 + ic * 9 + tap];
    }
    // transpose value conv: [oc32][ic64] -> [ic64][oc32]
    for (int i = g; i < 2048; i += gs) {
        vwT[i] = val_conv_w[(i & 31) * 64 + (i >> 5)];
    }
    // emb_h[p][j] = b1[j] + sum_e pt[p][e]*W1[64+e][j]
    for (int i = g; i < 2688; i += gs) {
        int j = i & 127, p = i >> 7;
        float a = mlp_b1[j];
        for (int e = 0; e < 16; e++)
            a += piece_table[p * 16 + e] * mlp_w1[(64 + e) * 128 + j];
        emb_h[i] = a;
    }
    if (g < 32) pooled[g] = 0.f;

    // stem conv 5->64, 3x3 SAME, bn, relu  (blocks 0..99, wave = position)
    if (blockIdx.x < 100) {
        int wv   = blockIdx.x * 4 + (threadIdx.x >> 6);  // 0..399
        int lane = threadIdx.x & 63;                     // = out channel
        int y = wv / 20, x = wv % 20;
        float acc = 0.f;
        for (int ic = 0; ic < 5; ic++) {
            #pragma unroll
            for (int t = 0; t < 9; t++) {
                int yy = y + t / 3 - 1, xx = x + t % 3 - 1;
                if ((unsigned)yy < 20u && (unsigned)xx < 20u)
                    acc += board[ic * 400 + yy * 20 + xx] * stem_w[lane * 45 + ic * 9 + t];
            }
        }
        xA[wv * 64 + lane] = fmaxf((acc + stem_b[lane]) * stem_s[lane] + stem_o[lane], 0.f);
    }
}

// ---------------- residual 3x3 conv (+ optional residual, + optional value head) ----------------
__global__ __launch_bounds__(256) void conv3x3_kernel(
    const float* __restrict__ in, float* __restrict__ out,
    const float* __restrict__ wTc, const float* __restrict__ bias,
    const float* __restrict__ scale, const float* __restrict__ offs,
    const float* __restrict__ resid,          // nullptr for conv1 of a block
    __hip_bfloat16* __restrict__ bf_out,      // nullptr except final conv
    const float* __restrict__ vwT, const float* __restrict__ vcb,
    float* __restrict__ pooled)
{
    extern __shared__ unsigned char smem[];
    float* lds = (float*)smem;                // [22][22][64] zero-padded input

    // zero-fill (borders), then stage interior
    float4 z = make_float4(0.f, 0.f, 0.f, 0.f);
    for (int i = threadIdx.x; i < 7744; i += 256) ((float4*)lds)[i] = z;
    __syncthreads();
    for (int i = threadIdx.x; i < 6400; i += 256) {
        float4 v = ((const float4*)in)[i];
        int fi = i * 4;
        int c = fi & 63, p = fi >> 6;
        int y = p / 20, x = p % 20;
        *(float4*)&lds[((y + 1) * 22 + (x + 1)) * 64 + c] = v;
    }
    __syncthreads();

    int wv   = blockIdx.x * 4 + (threadIdx.x >> 6);   // 0..199 (grid=50)
    int lane = threadIdx.x & 63;                      // out channel
    int p0 = wv * 2, p1 = p0 + 1;
    int y0 = p0 / 20, x0 = p0 % 20, y1 = p1 / 20, x1 = p1 % 20;
    float acc0 = 0.f, acc1 = 0.f;

    #pragma unroll 1
    for (int t = 0; t < 9; t++) {
        int dy = t / 3, dx = t % 3;
        int r0 = ((y0 + dy) * 22 + x0 + dx) * 64;
        int r1 = ((y1 + dy) * 22 + x1 + dx) * 64;
        #pragma unroll
        for (int g4 = 0; g4 < 16; g4++) {
            float4 a = *(const float4*)&lds[r0 + g4 * 4];
            float4 b = *(const float4*)&lds[r1 + g4 * 4];
            float w0 = wTc[((g4 * 4 + 0) * 9 + t) * 64 + lane];
            float w1 = wTc[((g4 * 4 + 1) * 9 + t) * 64 + lane];
            float w2 = wTc[((g4 * 4 + 2) * 9 + t) * 64 + lane];
            float w3 = wTc[((g4 * 4 + 3) * 9 + t) * 64 + lane];
            acc0 += a.x * w0; acc1 += b.x * w0;
            acc0 += a.y * w1; acc1 += b.y * w1;
            acc0 += a.z * w2; acc1 += b.z * w2;
            acc0 += a.w * w3; acc1 += b.w * w3;
        }
    }

    float s = scale[lane], o = offs[lane], bb = bias[lane];
    float v0 = (acc0 + bb) * s + o;
    float v1 = (acc1 + bb) * s + o;
    if (resid) { v0 += resid[p0 * 64 + lane]; v1 += resid[p1 * 64 + lane]; }
    v0 = fmaxf(v0, 0.f); v1 = fmaxf(v1, 0.f);
    out[p0 * 64 + lane] = v0;
    out[p1 * 64 + lane] = v1;

    if (bf_out) {
        // bf16 fmap with pitch 68 (pad cols 64..67 unused)
        bf_out[p0 * 68 + lane] = __float2bfloat16(v0);
        bf_out[p1 * 68 + lane] = __float2bfloat16(v1);

        // value head: 1x1 conv (64->32) + relu + sum over this block's 8 positions
        __syncthreads();                      // everyone done reading lds
        float* vl = lds;                      // reuse: [8][64] activations
        int w8 = threadIdx.x >> 6;
        vl[(w8 * 2 + 0) * 64 + lane] = v0;
        vl[(w8 * 2 + 1) * 64 + lane] = v1;
        __syncthreads();
        int oc = threadIdx.x & 31;
        int ps = threadIdx.x >> 5;            // 0..7
        float a = 0.f;
        for (int ic = 0; ic < 64; ic++) a += vl[ps * 64 + ic] * vwT[ic * 32 + oc];
        a = fmaxf(a + vcb[oc], 0.f);
        __syncthreads();
        vl[threadIdx.x] = a;
        __syncthreads();
        if (threadIdx.x < 32) {
            float s2 = 0.f;
            for (int q = 0; q < 8; q++) s2 += vl[q * 32 + threadIdx.x];
            atomicAdd(&pooled[threadIdx.x], s2);
        }
    }
}

// ---------------- policy head (+ value MLP on block 0) ----------------
__global__ __launch_bounds__(256) void policy_kernel(
    const __hip_bfloat16* __restrict__ fbf,
    const int* __restrict__ piece_id, const float* __restrict__ anchor,
    const int* __restrict__ num_cells, const float* __restrict__ size_f,
    const int* __restrict__ cells,
    const float* __restrict__ emb_h, const float* __restrict__ mlp_w1,
    const float* __restrict__ mlp_w2, const float* __restrict__ mlp_b2,
    float* __restrict__ out,
    const float* __restrict__ pooled, const float* __restrict__ self_rem,
    const float* __restrict__ opp_rem, const float* __restrict__ val_w1,
    const float* __restrict__ val_b1, const float* __restrict__ val_w2,
    const float* __restrict__ val_b2)
{
    extern __shared__ unsigned char smem[];
    ushort_t* lfm = (ushort_t*)smem;          // [400][68] bf16 fmap

    { // stage 27200 ushorts = 3400 uint4
        const uint4* src = (const uint4*)fbf;
        uint4* dst = (uint4*)lfm;
        for (int i = threadIdx.x; i < 3400; i += 256) dst[i] = src[i];
    }
    __syncthreads();

    // value head MLP (block 0, wave 0)
    if (blockIdx.x == 0 && threadIdx.x < 64) {
        int j = threadIdx.x;
        float acc = val_b1[j];
        for (int k = 0; k < 74; k++) {
            float vk = (k < 32) ? pooled[k] * (1.0f / 400.0f)
                                : ((k < 53) ? self_rem[k - 32] : opp_rem[k - 53]);
            acc += vk * val_w1[k * 64 + j];
        }
        float h = fmaxf(acc, 0.f);
        float prod = h * val_w2[j];
        for (int off = 32; off > 0; off >>= 1) prod += __shfl_xor(prod, off);
        if (j == 0) out[400000] = tanhf(prod + val_b2[0]);
    }

    const float b2 = mlp_b2[0];
    int stride = gridDim.x * blockDim.x;
    for (int m = blockIdx.x * blockDim.x + threadIdx.x; m < 400000; m += stride) {
        int   pid = piece_id[m];
        int   nc  = num_cells[m];
        float2 an = ((const float2*)anchor)[m];
        float sz  = size_f[m];

        float mv[64];
        #pragma unroll
        for (int c = 0; c < 64; c++) mv[c] = 0.f;

        for (int j = 0; j < nc; j++) {
            int2 cc = ((const int2*)cells)[m * 5 + j];   // (x, y)
            int base = (cc.y * 20 + cc.x) * 68;
            #pragma unroll
            for (int c8 = 0; c8 < 16; c8++) {            // 4 bf16 per uint2
                uint2 q = *(const uint2*)(lfm + base + c8 * 4);
                mv[c8 * 4 + 0] += __uint_as_float(q.x << 16);
                mv[c8 * 4 + 1] += __uint_as_float(q.x & 0xffff0000u);
                mv[c8 * 4 + 2] += __uint_as_float(q.y << 16);
                mv[c8 * 4 + 3] += __uint_as_float(q.y & 0xffff0000u);
            }
        }
        float scl = 1.0f / (float)nc;
        #pragma unroll
        for (int c = 0; c < 64; c++) mv[c] *= scl;

        float logit = b2;
        #pragma unroll 1
        for (int jc = 0; jc < 8; jc++) {
            float h[16];
            { // init from folded piece-emb + b1
                const float4* e4 = (const float4*)(emb_h + pid * 128 + jc * 16);
                #pragma unroll
                for (int i = 0; i < 4; i++) {
                    float4 t = e4[i];
                    h[4 * i + 0] = t.x; h[4 * i + 1] = t.y;
                    h[4 * i + 2] = t.z; h[4 * i + 3] = t.w;
                }
            }
            // move_vec contribution: weights uniform -> s_load + v_fmac
            #pragma unroll
            for (int k = 0; k < 64; k++) {
                const float* wr = mlp_w1 + k * 128 + jc * 16;
                #pragma unroll
                for (int i = 0; i < 16; i++) h[i] += mv[k] * wr[i];
            }
            { const float* wr = mlp_w1 + 80 * 128 + jc * 16;
              #pragma unroll
              for (int i = 0; i < 16; i++) h[i] += an.x * wr[i]; }
            { const float* wr = mlp_w1 + 81 * 128 + jc * 16;
              #pragma unroll
              for (int i = 0; i < 16; i++) h[i] += an.y * wr[i]; }
            { const float* wr = mlp_w1 + 82 * 128 + jc * 16;
              #pragma unroll
              for (int i = 0; i < 16; i++) h[i] += sz * wr[i]; }
            const float* w2r = mlp_w2 + jc * 16;
            #pragma unroll
            for (int i = 0; i < 16; i++) logit += fmaxf(h[i], 0.f) * w2r[i];
        }
        out[m] = logit;
    }
}

// ---------------------------------------------------------------------------
extern "C" void kernel_launch(void* const* d_in, const int* in_sizes, int n_in,
                              void* d_out, int out_size, void* d_ws, size_t ws_size,
                              hipStream_t stream) {
    const float* board      = (const float*)d_in[0];
    const float* self_rem   = (const float*)d_in[1];
    const float* opp_rem    = (const float*)d_in[2];
    const int*   piece_id   = (const int*)  d_in[3];
    const float* anchor     = (const float*)d_in[4];
    const int*   num_cells  = (const int*)  d_in[5];
    const float* size_f     = (const float*)d_in[6];
    const int*   cells      = (const int*)  d_in[7];
    const float* stem_w     = (const float*)d_in[8];
    const float* stem_b     = (const float*)d_in[9];
    const float* stem_s     = (const float*)d_in[10];
    const float* stem_o     = (const float*)d_in[11];
    const float* blk_w1     = (const float*)d_in[12];
    const float* blk_b1     = (const float*)d_in[13];
    const float* blk_s1     = (const float*)d_in[14];
    const float* blk_o1     = (const float*)d_in[15];
    const float* blk_w2     = (const float*)d_in[16];
    const float* blk_b2     = (const float*)d_in[17];
    const float* blk_s2     = (const float*)d_in[18];
    const float* blk_o2     = (const float*)d_in[19];
    const float* piece_tab  = (const float*)d_in[20];
    const float* mlp_w1     = (const float*)d_in[21];
    const float* mlp_b1     = (const float*)d_in[22];
    const float* mlp_w2     = (const float*)d_in[23];
    const float* mlp_b2     = (const float*)d_in[24];
    const float* val_conv_w = (const float*)d_in[25];
    const float* val_conv_b = (const float*)d_in[26];
    const float* val_w1     = (const float*)d_in[27];
    const float* val_b1     = (const float*)d_in[28];
    const float* val_w2     = (const float*)d_in[29];
    const float* val_b2     = (const float*)d_in[30];
    float* out = (float*)d_out;

    float* ws     = (float*)d_ws;
    float* xA     = ws;
    float* xB     = ws + 25600;
    float* wT     = ws + 51200;
    float* vwT    = ws + 346112;
    float* emb_h  = ws + 348160;
    float* pooled = ws + 350848;
    __hip_bfloat16* fbf = (__hip_bfloat16*)(ws + 350880);

    // allow >64KB dynamic LDS for the conv kernel (defensive; no-op if already allowed)
    static bool attr_set = false;
    (void)attr_set;
    hipFuncSetAttribute((const void*)conv3x3_kernel,
                        hipFuncAttributeMaxDynamicSharedMemorySize, 123904);

    prep_stem_kernel<<<128, 256, 0, stream>>>(
        board, stem_w, stem_b, stem_s, stem_o, xA,
        blk_w1, blk_w2, val_conv_w, piece_tab, mlp_w1, mlp_b1,
        wT, vwT, emb_h, pooled);

    for (int l = 0; l < 4; l++) {
        bool last = (l == 3);
        conv3x3_kernel<<<50, 256, 123904, stream>>>(
            xA, xB, wT + (2 * l) * 36864,
            blk_b1 + l * 64, blk_s1 + l * 64, blk_o1 + l * 64,
            nullptr, nullptr, vwT, val_conv_b, pooled);
        conv3x3_kernel<<<50, 256, 123904, stream>>>(
            xB, xA, wT + (2 * l + 1) * 36864,
            blk_b2 + l * 64, blk_s2 + l * 64, blk_o2 + l * 64,
            xA, last ? fbf : nullptr, vwT, val_conv_b, pooled);
    }

    policy_kernel<<<512, 256, 54400, stream>>>(
        fbf, piece_id, anchor, num_cells, size_f, cells,
        emb_h, mlp_w1, mlp_w2, mlp_b2, out,
        pooled, self_rem, opp_rem, val_w1, val_b1, val_w2, val_b2);
}

// Round 7
// 364.752 us; speedup vs baseline: 1.3097x; 1.3097x over previous
//
#include <hip/hip_runtime.h>
#include <hip/hip_bf16.h>

typedef unsigned short ushort_t;
typedef __attribute__((ext_vector_type(8))) short short8;
typedef __attribute__((ext_vector_type(4))) float f32x4;

static __device__ inline ushort_t f2bfu(float f) {
    __hip_bfloat16 h = __float2bfloat16(f);
    ushort_t u; __builtin_memcpy(&u, &h, 2); return u;
}
static __device__ inline float bflo(unsigned int u) { return __uint_as_float(u << 16); }
static __device__ inline float bfhi(unsigned int u) { return __uint_as_float(u & 0xffff0000u); }

// ---------------------------------------------------------------------------
// Workspace (floats):
//   xA @0 (25600) | xB @25600 (25600) | wT @51200 (294912) | vwT @346112 (2048)
//   pooled @348160 (32) | fbf(bf16[400][64]) @348192 (12800) |
//   W1bf(bf16[96][128]) @360992 (6144) | ptbf(bf16[21][16]) @367136 (168)
// ---------------------------------------------------------------------------

// ---------------- prep (+ stem on blocks 0..99) ----------------
__global__ __launch_bounds__(256) void prep_stem_kernel(
    const float* __restrict__ board,
    const float* __restrict__ stem_w, const float* __restrict__ stem_b,
    const float* __restrict__ stem_s, const float* __restrict__ stem_o,
    float* __restrict__ xA,
    const float* __restrict__ blk_w1, const float* __restrict__ blk_w2,
    const float* __restrict__ val_conv_w, const float* __restrict__ piece_table,
    const float* __restrict__ mlp_w1,
    float* __restrict__ wT, float* __restrict__ vwT,
    ushort_t* __restrict__ W1bfu, ushort_t* __restrict__ ptbfu,
    float* __restrict__ pooled)
{
    int g  = blockIdx.x * blockDim.x + threadIdx.x;
    int gs = gridDim.x * blockDim.x;

    // conv weights [l][oc][ic][9] -> [l][ic][tap][oc]; coalesced READ, scattered write
    for (int i = g; i < 294912; i += gs) {
        int l   = i / 36864;
        int rem = i - l * 36864;          // = oc*576 + ic*9 + tap
        int oc  = rem / 576;
        int r2  = rem - oc * 576;         // ic*9 + tap
        const float* src = (l & 1) ? blk_w2 : blk_w1;
        float v = src[(l >> 1) * 36864 + rem];
        wT[l * 36864 + r2 * 64 + oc] = v;
    }
    // value conv: [oc32][ic64] -> [ic64][oc32]
    for (int i = g; i < 2048; i += gs)
        vwT[i] = val_conv_w[(i & 31) * 64 + (i >> 5)];
    // W1 bf16, padded to 96 rows (rows 83..95 zero). row-major [96][128]
    for (int i = g; i < 12288; i += gs)
        W1bfu[i] = (i < 83 * 128) ? f2bfu(mlp_w1[i]) : (ushort_t)0;
    // piece table bf16
    for (int i = g; i < 336; i += gs)
        ptbfu[i] = f2bfu(piece_table[i]);
    if (g < 32) pooled[g] = 0.f;

    // stem conv 5->64, 3x3 SAME, bn, relu (blocks 0..99, wave = position)
    if (blockIdx.x < 100) {
        int wv   = blockIdx.x * 4 + (threadIdx.x >> 6);
        int lane = threadIdx.x & 63;
        int y = wv / 20, x = wv % 20;
        float acc = 0.f;
        for (int ic = 0; ic < 5; ic++) {
            #pragma unroll
            for (int t = 0; t < 9; t++) {
                int yy = y + t / 3 - 1, xx = x + t % 3 - 1;
                if ((unsigned)yy < 20u && (unsigned)xx < 20u)
                    acc += board[ic * 400 + yy * 20 + xx] * stem_w[lane * 45 + ic * 9 + t];
            }
        }
        xA[wv * 64 + lane] = fmaxf((acc + stem_b[lane]) * stem_s[lane] + stem_o[lane], 0.f);
    }
}

// ---------------- residual 3x3 conv: 100 blocks, wave = 1 position ----------------
__global__ __launch_bounds__(256) void conv3x3_kernel(
    const float* __restrict__ in, float* __restrict__ out,
    const float* __restrict__ wTc, const float* __restrict__ bias,
    const float* __restrict__ scale, const float* __restrict__ offs,
    const float* __restrict__ resid,
    __hip_bfloat16* __restrict__ bf_out,           // non-null on final conv
    const float* __restrict__ vwT, const float* __restrict__ vcb,
    float* __restrict__ pooled)
{
    __shared__ float lds[1152 + 384];               // [3 rows][6 cols][64ch] stage
    int tid = threadIdx.x;
    int by = blockIdx.x / 5, x0 = (blockIdx.x % 5) * 4;

    for (int i4 = tid; i4 < 288; i4 += 256) {       // 288 float4
        int rr = i4 >> 4, cc4 = i4 & 15;
        int ry = rr / 6, rx = rr - ry * 6;
        int gy = by - 1 + ry, gx = x0 - 1 + rx;
        float4 v = make_float4(0.f, 0.f, 0.f, 0.f);
        if ((unsigned)gy < 20u && (unsigned)gx < 20u)
            v = *(const float4*)&in[(gy * 20 + gx) * 64 + cc4 * 4];
        *(float4*)&lds[rr * 64 + cc4 * 4] = v;
    }
    __syncthreads();

    int w = tid >> 6, lane = tid & 63;
    int p = by * 20 + x0 + w;
    float acc0 = 0.f, acc1 = 0.f;                   // 2 chains for ILP

    #pragma unroll 3
    for (int t = 0; t < 9; t++) {
        int dy = t / 3, dx = t - dy * 3;
        const float* lrow = &lds[(dy * 6 + w + dx) * 64];
        const float* wrow = &wTc[t * 64 + lane];
        #pragma unroll
        for (int ic4 = 0; ic4 < 16; ic4++) {
            float4 a = *(const float4*)&lrow[ic4 * 4];
            float w0 = wrow[(ic4 * 4 + 0) * 576];
            float w1 = wrow[(ic4 * 4 + 1) * 576];
            float w2 = wrow[(ic4 * 4 + 2) * 576];
            float w3 = wrow[(ic4 * 4 + 3) * 576];
            acc0 += a.x * w0; acc1 += a.y * w1;
            acc0 += a.z * w2; acc1 += a.w * w3;
        }
    }

    float v0 = ((acc0 + acc1) + bias[lane]) * scale[lane] + offs[lane];
    if (resid) v0 += resid[p * 64 + lane];
    v0 = fmaxf(v0, 0.f);
    out[p * 64 + lane] = v0;

    if (bf_out) {
        bf_out[p * 64 + lane] = __float2bfloat16(v0);
        // value head: 1x1 conv 64->32 + relu + pooled-sum over this block's 4 positions
        __syncthreads();
        lds[w * 64 + lane] = v0;
        __syncthreads();
        if (tid < 128) {
            int ps = tid >> 5, oc = tid & 31;
            float a = 0.f;
            for (int ic = 0; ic < 64; ic++) a += lds[ps * 64 + ic] * vwT[ic * 32 + oc];
            lds[256 + tid] = fmaxf(a + vcb[oc], 0.f);
        }
        __syncthreads();
        if (tid < 32) {
            float s = lds[256 + tid] + lds[288 + tid] + lds[320 + tid] + lds[352 + tid];
            atomicAdd(&pooled[tid], s);
        }
    }
}

// ---------------- policy head: MFMA GEMM (+ value MLP on block 0) ----------------
__global__ __launch_bounds__(256, 2) void policy_kernel(
    const ushort_t* __restrict__ fbf,
    const int* __restrict__ piece_id, const float* __restrict__ anchor,
    const int* __restrict__ num_cells, const float* __restrict__ size_f,
    const int* __restrict__ cells,
    const ushort_t* __restrict__ W1bfu, const ushort_t* __restrict__ ptbfu,
    const float* __restrict__ b1, const float* __restrict__ w2,
    const float* __restrict__ b2p,
    float* __restrict__ out,
    const float* __restrict__ pooled, const float* __restrict__ self_rem,
    const float* __restrict__ opp_rem, const float* __restrict__ val_w1,
    const float* __restrict__ val_b1, const float* __restrict__ val_w2,
    const float* __restrict__ val_b2)
{
    extern __shared__ ushort_t lfm[];   // fmap 25600 ush (swizzled) + 4 x [16][104] F

    { // stage fmap with XOR-swizzle of the 16B-unit index within each row
        const uint4* src = (const uint4*)fbf;
        uint4* dst = (uint4*)lfm;
        for (int i = threadIdx.x; i < 3200; i += 256) {
            int row = i >> 3, u = i & 7;
            dst[(row << 3) | (u ^ (row & 7))] = src[i];
        }
    }
    __syncthreads();

    // value head MLP (block 0, first wave)
    if (blockIdx.x == 0 && threadIdx.x < 64) {
        int j = threadIdx.x;
        float acc = val_b1[j];
        for (int k = 0; k < 74; k++) {
            float vk = (k < 32) ? pooled[k] * (1.0f / 400.0f)
                                : ((k < 53) ? self_rem[k - 32] : opp_rem[k - 53]);
            acc += vk * val_w1[k * 64 + j];
        }
        float h = fmaxf(acc, 0.f);
        float prod = h * val_w2[j];
        for (int off = 32; off > 0; off >>= 1) prod += __shfl_xor(prod, off);
        if (j == 0) out[400000] = tanhf(prod + val_b2[0]);
    }

    int l  = threadIdx.x & 63, w = threadIdx.x >> 6;
    int cl = l & 15, kq = l >> 4;       // MFMA col / k-quarter
    int mi = l >> 2, sl = l & 3;        // gather: move-in-tile / 16-ch slot
    ushort_t* Fl = lfm + 25600 + w * 1664;   // per-wave [16][104] bf16

    // preload W1 B-fragments: bfr[ks][nt][e] = W1bf[ks*32+kq*8+e][nt*16+cl]
    short8 bfr[3][8];
    #pragma unroll
    for (int ks = 0; ks < 3; ks++) {
        #pragma unroll
        for (int nt = 0; nt < 8; nt++) {
            short8 s;
            #pragma unroll
            for (int e = 0; e < 8; e++)
                s[e] = (short)W1bfu[(ks * 32 + kq * 8 + e) * 128 + nt * 16 + cl];
            bfr[ks][nt] = s;
        }
    }
    float b1v[8], w2v[8];
    #pragma unroll
    for (int nt = 0; nt < 8; nt++) { b1v[nt] = b1[nt * 16 + cl]; w2v[nt] = w2[nt * 16 + cl]; }
    const float b2 = b2p[0];

    int gw = blockIdx.x * 4 + w;
    for (int m0 = gw * 16; m0 < 400000; m0 += 2048 * 16) {
        int m = m0 + mi;
        int   pid = piece_id[m];
        int   nc  = num_cells[m];
        float2 an = ((const float2*)anchor)[m];
        float  sz = size_f[m];

        // gather-mean: this lane accumulates channels [sl*16, sl*16+16)
        float gacc[16];
        #pragma unroll
        for (int c = 0; c < 16; c++) gacc[c] = 0.f;
        for (int j = 0; j < nc; j++) {
            int2 cc = ((const int2*)cells)[m * 5 + j];
            int pc = cc.y * 20 + cc.x;
            int b7 = pc & 7;
            uint4 qa = *(const uint4*)(lfm + (pc << 6) + (((sl << 1)    ) ^ b7) * 8);
            uint4 qb = *(const uint4*)(lfm + (pc << 6) + (((sl << 1) | 1) ^ b7) * 8);
            gacc[0] += bflo(qa.x); gacc[1] += bfhi(qa.x);
            gacc[2] += bflo(qa.y); gacc[3] += bfhi(qa.y);
            gacc[4] += bflo(qa.z); gacc[5] += bfhi(qa.z);
            gacc[6] += bflo(qa.w); gacc[7] += bfhi(qa.w);
            gacc[8]  += bflo(qb.x); gacc[9]  += bfhi(qb.x);
            gacc[10] += bflo(qb.y); gacc[11] += bfhi(qb.y);
            gacc[12] += bflo(qb.z); gacc[13] += bfhi(qb.z);
            gacc[14] += bflo(qb.w); gacc[15] += bfhi(qb.w);
        }
        float scl = 1.0f / (float)nc;
        unsigned int pk[8];
        #pragma unroll
        for (int k = 0; k < 8; k++)
            pk[k] = (unsigned int)f2bfu(gacc[2 * k] * scl)
                  | ((unsigned int)f2bfu(gacc[2 * k + 1] * scl) << 16);
        *(uint4*)(Fl + mi * 104 + sl * 16)     = make_uint4(pk[0], pk[1], pk[2], pk[3]);
        *(uint4*)(Fl + mi * 104 + sl * 16 + 8) = make_uint4(pk[4], pk[5], pk[6], pk[7]);
        if (sl == 0) { // piece embedding -> cols 64..79
            const uint4* pt = (const uint4*)ptbfu;
            *(uint4*)(Fl + mi * 104 + 64) = pt[pid * 2];
            *(uint4*)(Fl + mi * 104 + 72) = pt[pid * 2 + 1];
        }
        if (sl == 1) { // anchor, size, zero-pad -> cols 80..95
            unsigned int u0 = (unsigned int)f2bfu(an.x) | ((unsigned int)f2bfu(an.y) << 16);
            unsigned int u1 = (unsigned int)f2bfu(sz);
            *(uint4*)(Fl + mi * 104 + 80) = make_uint4(u0, u1, 0u, 0u);
            *(uint4*)(Fl + mi * 104 + 88) = make_uint4(0u, 0u, 0u, 0u);
        }
        // wave-local fence: F writes (cross-lane) must land before A-frag reads
        asm volatile("s_waitcnt lgkmcnt(0)" ::: "memory");

        short8 af0 = *(const short8*)(Fl + cl * 104 +      kq * 8);
        short8 af1 = *(const short8*)(Fl + cl * 104 + 32 + kq * 8);
        short8 af2 = *(const short8*)(Fl + cl * 104 + 64 + kq * 8);

        f32x4 acc[8];
        #pragma unroll
        for (int nt = 0; nt < 8; nt++) acc[nt] = (f32x4)0.f;
        #pragma unroll
        for (int nt = 0; nt < 8; nt++) {
            acc[nt] = __builtin_amdgcn_mfma_f32_16x16x32_bf16(af0, bfr[0][nt], acc[nt], 0, 0, 0);
            acc[nt] = __builtin_amdgcn_mfma_f32_16x16x32_bf16(af1, bfr[1][nt], acc[nt], 0, 0, 0);
            acc[nt] = __builtin_amdgcn_mfma_f32_16x16x32_bf16(af2, bfr[2][nt], acc[nt], 0, 0, 0);
        }

        // epilogue: relu(h)+w2, reduce over 16 col-lanes, write 16 logits
        float p0 = 0.f, p1 = 0.f, p2 = 0.f, p3 = 0.f;
        #pragma unroll
        for (int nt = 0; nt < 8; nt++) {
            p0 += fmaxf(acc[nt].x + b1v[nt], 0.f) * w2v[nt];
            p1 += fmaxf(acc[nt].y + b1v[nt], 0.f) * w2v[nt];
            p2 += fmaxf(acc[nt].z + b1v[nt], 0.f) * w2v[nt];
            p3 += fmaxf(acc[nt].w + b1v[nt], 0.f) * w2v[nt];
        }
        #pragma unroll
        for (int off = 1; off < 16; off <<= 1) {
            p0 += __shfl_xor(p0, off); p1 += __shfl_xor(p1, off);
            p2 += __shfl_xor(p2, off); p3 += __shfl_xor(p3, off);
        }
        if (cl < 4) {
            float v = p0;
            if (cl == 1) v = p1; else if (cl == 2) v = p2; else if (cl == 3) v = p3;
            out[m0 + kq * 4 + cl] = v + b2;
        }
    }
}

// ---------------------------------------------------------------------------
extern "C" void kernel_launch(void* const* d_in, const int* in_sizes, int n_in,
                              void* d_out, int out_size, void* d_ws, size_t ws_size,
                              hipStream_t stream) {
    const float* board      = (const float*)d_in[0];
    const float* self_rem   = (const float*)d_in[1];
    const float* opp_rem    = (const float*)d_in[2];
    const int*   piece_id   = (const int*)  d_in[3];
    const float* anchor     = (const float*)d_in[4];
    const int*   num_cells  = (const int*)  d_in[5];
    const float* size_f     = (const float*)d_in[6];
    const int*   cells      = (const int*)  d_in[7];
    const float* stem_w     = (const float*)d_in[8];
    const float* stem_b     = (const float*)d_in[9];
    const float* stem_s     = (const float*)d_in[10];
    const float* stem_o     = (const float*)d_in[11];
    const float* blk_w1     = (const float*)d_in[12];
    const float* blk_b1     = (const float*)d_in[13];
    const float* blk_s1     = (const float*)d_in[14];
    const float* blk_o1     = (const float*)d_in[15];
    const float* blk_w2     = (const float*)d_in[16];
    const float* blk_b2     = (const float*)d_in[17];
    const float* blk_s2     = (const float*)d_in[18];
    const float* blk_o2     = (const float*)d_in[19];
    const float* piece_tab  = (const float*)d_in[20];
    const float* mlp_w1     = (const float*)d_in[21];
    const float* mlp_b1     = (const float*)d_in[22];
    const float* mlp_w2     = (const float*)d_in[23];
    const float* mlp_b2     = (const float*)d_in[24];
    const float* val_conv_w = (const float*)d_in[25];
    const float* val_conv_b = (const float*)d_in[26];
    const float* val_w1     = (const float*)d_in[27];
    const float* val_b1     = (const float*)d_in[28];
    const float* val_w2     = (const float*)d_in[29];
    const float* val_b2     = (const float*)d_in[30];
    float* out = (float*)d_out;

    float* ws     = (float*)d_ws;
    float* xA     = ws;
    float* xB     = ws + 25600;
    float* wT     = ws + 51200;
    float* vwT    = ws + 346112;
    float* pooled = ws + 348160;
    ushort_t*       fbf   = (ushort_t*)(ws + 348192);
    ushort_t*       W1bfu = (ushort_t*)(ws + 360992);
    ushort_t*       ptbfu = (ushort_t*)(ws + 367136);

    (void)hipFuncSetAttribute((const void*)policy_kernel,
                              hipFuncAttributeMaxDynamicSharedMemorySize, 65536);

    prep_stem_kernel<<<256, 256, 0, stream>>>(
        board, stem_w, stem_b, stem_s, stem_o, xA,
        blk_w1, blk_w2, val_conv_w, piece_tab, mlp_w1,
        wT, vwT, W1bfu, ptbfu, pooled);

    for (int l = 0; l < 4; l++) {
        bool last = (l == 3);
        conv3x3_kernel<<<100, 256, 0, stream>>>(
            xA, xB, wT + (2 * l) * 36864,
            blk_b1 + l * 64, blk_s1 + l * 64, blk_o1 + l * 64,
            nullptr, nullptr, vwT, val_conv_b, pooled);
        conv3x3_kernel<<<100, 256, 0, stream>>>(
            xB, xA, wT + (2 * l + 1) * 36864,
            blk_b2 + l * 64, blk_s2 + l * 64, blk_o2 + l * 64,
            xA, last ? (__hip_bfloat16*)fbf : nullptr, vwT, val_conv_b, pooled);
    }

    policy_kernel<<<512, 256, 64512, stream>>>(
        fbf, piece_id, anchor, num_cells, size_f, cells,
        W1bfu, ptbfu, mlp_b1, mlp_w2, mlp_b2, out,
        pooled, self_rem, opp_rem, val_w1, val_b1, val_w2, val_b2);
}